// Round 3
// baseline (247.449 us; speedup 1.0000x reference)
//
#include <hip/hip_runtime.h>
#include <math.h>

// MultiHeadSelfAttention: B=2, S=2048, E=1024, H=16, D=64
// Reference computes Q@V^T (source bug, K unused) -> softmax -> @V.
// Round 2: fp16 MFMA version. conv kernels -> fused Q/V proj GEMM (mfma) ->
// flash attention (mfma), softmax fp32, accumulate fp32.

constexpr int BATCH = 2;
constexpr int SEQ   = 2048;
constexpr int EMB   = 1024;
constexpr int NHEAD = 16;
constexpr int HDIM  = 64;
constexpr int HID   = 1024;

typedef __attribute__((ext_vector_type(8))) _Float16 half8;
typedef __attribute__((ext_vector_type(4))) float    f32x4;

#define MFMA16(a, b, c) __builtin_amdgcn_mfma_f32_16x16x32_f16((a), (b), (c), 0, 0, 0)

// LDS tile leading dim (in halves): 72 -> 144 B rows, 16B aligned, frag reads
// land on distinct-bank rows (36 dwords/row).
constexpr int LDT = 72;

// VT swizzled index (halves): d in [0,64), k in [0,64).
// 16B chunk swizzle: chunk' = (k/8 + d/8) & 7. Makes transpose writes ~2-way
// (free) at the cost of ~4-way frag reads.
__device__ __forceinline__ int vt_idx(int d, int k) {
    return (d << 6) + ((((k >> 3) + (d >> 3)) & 7) << 3) + (k & 7);
}

__device__ __forceinline__ _Float16 f2h(float f) { return (_Float16)f; }

// ---------------------------------------------------------------------------
// conv_x: fp32 -> fp16 elementwise (X)
// ---------------------------------------------------------------------------
__global__ __launch_bounds__(256) void conv_x_kernel(
    const float* __restrict__ X, _Float16* __restrict__ Xb, int n4)
{
    union Pack { uint2 q; _Float16 e[4]; };
    int idx = blockIdx.x * 256 + threadIdx.x;
    int stride = gridDim.x * 256;
    for (int i = idx; i < n4; i += stride) {
        float4 v = ((const float4*)X)[i];
        Pack p;
        p.e[0] = f2h(v.x); p.e[1] = f2h(v.y);
        p.e[2] = f2h(v.z); p.e[3] = f2h(v.w);
        ((uint2*)Xb)[i] = p.q;
    }
}

// ---------------------------------------------------------------------------
// conv_wt: W [K=1024][N=1024] fp32  ->  WT [N][K] fp16 (transpose via LDS)
// grid (N/64, K/64), 256 threads.
// ---------------------------------------------------------------------------
__global__ __launch_bounds__(256) void conv_wt_kernel(
    const float* __restrict__ W, _Float16* __restrict__ WT)
{
    __shared__ _Float16 T[64 * 68];
    const int tid = threadIdx.x;
    const int n0 = blockIdx.x * 64;
    const int k0 = blockIdx.y * 64;

    #pragma unroll
    for (int i = 0; i < 4; ++i) {
        const int u = tid + i * 256;
        const int r = u >> 4;              // 0..63 (k row)
        const int c4 = (u & 15) << 2;      // 0..60 (n col)
        const float4 v = *(const float4*)&W[(size_t)(k0 + r) * HID + n0 + c4];
        T[r * 68 + c4 + 0] = f2h(v.x);
        T[r * 68 + c4 + 1] = f2h(v.y);
        T[r * 68 + c4 + 2] = f2h(v.z);
        T[r * 68 + c4 + 3] = f2h(v.w);
    }
    __syncthreads();

    union Pack { uint4 q; _Float16 e[8]; };
    #pragma unroll
    for (int i = 0; i < 2; ++i) {
        const int u = tid + i * 256;
        const int n = u >> 3;              // 0..63
        const int kc = (u & 7) << 3;       // 0..56
        Pack p;
        #pragma unroll
        for (int j = 0; j < 8; ++j) p.e[j] = T[(kc + j) * 68 + n];
        *(uint4*)&WT[(size_t)(n0 + n) * EMB + k0 + kc] = p.q;
    }
}

// ---------------------------------------------------------------------------
// proj: Q = Xb@WTq^T + bq, V = Xb@WTv^T + bv  -> fp16 [B][H][S][D]
// M=4096, N=64/head, K=1024. Block: 128x64 tile, 4 waves (32 M-rows each),
// BK=64. mfma 16x16x32 f16.
// ---------------------------------------------------------------------------
__global__ __launch_bounds__(256) void proj_kernel(
    const _Float16* __restrict__ Xb, const _Float16* __restrict__ WTq,
    const _Float16* __restrict__ WTv, const float* __restrict__ bq,
    const float* __restrict__ bv, _Float16* __restrict__ Qo,
    _Float16* __restrict__ Vo)
{
    __shared__ __align__(16) _Float16 Xs[128 * LDT];
    __shared__ __align__(16) _Float16 Wqs[64 * LDT];
    __shared__ __align__(16) _Float16 Wvs[64 * LDT];

    const int tid  = threadIdx.x;
    const int lane = tid & 63;
    const int w    = tid >> 6;           // wave 0..3
    const int h    = blockIdx.x;
    const int m0   = blockIdx.y * 128;
    const int n0   = h * HDIM;
    const int l15  = lane & 15;
    const int l4   = lane >> 4;          // 0..3

    f32x4 aq[2][4], av[2][4];
    #pragma unroll
    for (int mt = 0; mt < 2; ++mt)
        #pragma unroll
        for (int nt = 0; nt < 4; ++nt) {
            aq[mt][nt] = f32x4{0.f, 0.f, 0.f, 0.f};
            av[mt][nt] = f32x4{0.f, 0.f, 0.f, 0.f};
        }

    for (int k0 = 0; k0 < EMB; k0 += 64) {
        #pragma unroll
        for (int i = 0; i < 4; ++i) {
            const int u = tid + i * 256;          // 0..1023
            const int r = u >> 3;                 // 0..127
            const int c8 = (u & 7) << 3;          // 0..56
            *(uint4*)&Xs[r * LDT + c8] =
                *(const uint4*)&Xb[(size_t)(m0 + r) * EMB + k0 + c8];
        }
        #pragma unroll
        for (int i = 0; i < 2; ++i) {
            const int u = tid + i * 256;          // 0..511
            const int r = u >> 3;                 // 0..63
            const int c8 = (u & 7) << 3;
            *(uint4*)&Wqs[r * LDT + c8] =
                *(const uint4*)&WTq[(size_t)(n0 + r) * EMB + k0 + c8];
            *(uint4*)&Wvs[r * LDT + c8] =
                *(const uint4*)&WTv[(size_t)(n0 + r) * EMB + k0 + c8];
        }
        __syncthreads();

        #pragma unroll
        for (int kd = 0; kd < 2; ++kd) {
            const int ko = kd * 32 + l4 * 8;
            half8 xa0 = *(const half8*)&Xs[(w * 32 + l15) * LDT + ko];
            half8 xa1 = *(const half8*)&Xs[(w * 32 + 16 + l15) * LDT + ko];
            #pragma unroll
            for (int nt = 0; nt < 4; ++nt) {
                half8 wq = *(const half8*)&Wqs[(nt * 16 + l15) * LDT + ko];
                half8 wv = *(const half8*)&Wvs[(nt * 16 + l15) * LDT + ko];
                aq[0][nt] = MFMA16(xa0, wq, aq[0][nt]);
                aq[1][nt] = MFMA16(xa1, wq, aq[1][nt]);
                av[0][nt] = MFMA16(xa0, wv, av[0][nt]);
                av[1][nt] = MFMA16(xa1, wv, av[1][nt]);
            }
        }
        __syncthreads();
    }

    // epilogue: bias (fp32) + convert + scatter to [B][H][S][D]
    #pragma unroll
    for (int nt = 0; nt < 4; ++nt) {
        const float bqv = bq[n0 + nt * 16 + l15];
        const float bvv = bv[n0 + nt * 16 + l15];
        #pragma unroll
        for (int mt = 0; mt < 2; ++mt)
            #pragma unroll
            for (int r = 0; r < 4; ++r) {
                const int m = m0 + w * 32 + mt * 16 + l4 * 4 + r;
                const int bb = m >> 11;
                const int s  = m & (SEQ - 1);
                const size_t base =
                    ((size_t)(bb * NHEAD + h) * SEQ + s) * HDIM + nt * 16 + l15;
                Qo[base] = f2h(aq[mt][nt][r] + bqv);
                Vo[base] = f2h(av[mt][nt][r] + bvv);
            }
    }
}

// ---------------------------------------------------------------------------
// attn: per (b,h) flash attention, scores = Q@V^T/8 (source bug), softmax,
// @V. 64 Q-rows per block, 4 waves x 16 rows, KV tiles of 64. mfma f16.
// ---------------------------------------------------------------------------
__global__ __launch_bounds__(256) void attn_kernel(
    const _Float16* __restrict__ Qw, const _Float16* __restrict__ Vw,
    float* __restrict__ out)
{
    __shared__ __align__(16) _Float16 Qs[64 * LDT];
    __shared__ __align__(16) _Float16 Vs[64 * LDT];
    __shared__ __align__(16) _Float16 VTs[64 * 64];   // swizzled, see vt_idx
    __shared__ __align__(16) _Float16 Ps[64 * LDT];

    const int tid  = threadIdx.x;
    const int lane = tid & 63;
    const int w    = tid >> 6;
    const int l15  = lane & 15;
    const int l4   = lane >> 4;
    const int qb   = blockIdx.x;          // 0..31
    const int bh   = blockIdx.y;          // 0..31
    const int b    = bh >> 4;
    const int h    = bh & (NHEAD - 1);
    const int s0   = qb * 64;

    const _Float16* Qp = Qw + (size_t)bh * SEQ * HDIM;
    const _Float16* Vp = Vw + (size_t)bh * SEQ * HDIM;

    union Pack { uint4 q; _Float16 e[8]; };

    // stage V tile t into Vs (row-major) + VTs (swizzled transpose)
    auto stageV = [&](int t) {
        #pragma unroll
        for (int i = 0; i < 2; ++i) {
            const int u = tid + i * 256;       // 0..511
            const int r = u >> 3;              // v-row 0..63
            const int c8 = (u & 7) << 3;       // d 0..56
            Pack p;
            p.q = *(const uint4*)&Vp[(size_t)(t * 64 + r) * HDIM + c8];
            *(uint4*)&Vs[r * LDT + c8] = p.q;
            #pragma unroll
            for (int j = 0; j < 8; ++j)
                VTs[vt_idx(c8 + j, r)] = p.e[j];
        }
    };

    // load Q tile
    #pragma unroll
    for (int i = 0; i < 2; ++i) {
        const int u = tid + i * 256;
        const int r = u >> 3;
        const int c8 = (u & 7) << 3;
        *(uint4*)&Qs[r * LDT + c8] =
            *(const uint4*)&Qp[(size_t)(s0 + r) * HDIM + c8];
    }
    stageV(0);
    __syncthreads();

    // hoist Q A-frags (wave-invariant across kv loop)
    const half8 qa0 = *(const half8*)&Qs[(w * 16 + l15) * LDT + l4 * 8];
    const half8 qa1 = *(const half8*)&Qs[(w * 16 + l15) * LDT + 32 + l4 * 8];

    f32x4 acc_o[4];
    #pragma unroll
    for (int dt = 0; dt < 4; ++dt) acc_o[dt] = f32x4{0.f, 0.f, 0.f, 0.f};
    float m_i[4] = {-INFINITY, -INFINITY, -INFINITY, -INFINITY};
    float l_i[4] = {0.f, 0.f, 0.f, 0.f};

    const int prow_base = (w * 16 + l4 * 4) * LDT + l15;  // P write base
    const int pa_row = (w * 16 + l15) * LDT;               // P read row base

    for (int t = 0; t < SEQ / 64; ++t) {
        // ---- QK^T (V acts as B^T: both operands row-major [rows][d]) ----
        f32x4 acc_s[4];
        #pragma unroll
        for (int nt = 0; nt < 4; ++nt) acc_s[nt] = f32x4{0.f, 0.f, 0.f, 0.f};
        #pragma unroll
        for (int nt = 0; nt < 4; ++nt) {
            half8 vb0 = *(const half8*)&Vs[(nt * 16 + l15) * LDT + l4 * 8];
            half8 vb1 = *(const half8*)&Vs[(nt * 16 + l15) * LDT + 32 + l4 * 8];
            acc_s[nt] = MFMA16(qa0, vb0, acc_s[nt]);
            acc_s[nt] = MFMA16(qa1, vb1, acc_s[nt]);
        }

        // ---- online softmax (fp32), rows owned by 16-lane groups ----
        #pragma unroll
        for (int r = 0; r < 4; ++r) {
            float sA = acc_s[0][r] * 0.125f;
            float sB = acc_s[1][r] * 0.125f;
            float sC = acc_s[2][r] * 0.125f;
            float sD = acc_s[3][r] * 0.125f;
            float mloc = fmaxf(fmaxf(sA, sB), fmaxf(sC, sD));
            #pragma unroll
            for (int off = 1; off < 16; off <<= 1)
                mloc = fmaxf(mloc, __shfl_xor(mloc, off));
            const float mnew = fmaxf(m_i[r], mloc);
            const float corr = __expf(m_i[r] - mnew);
            const float p0 = __expf(sA - mnew);
            const float p1 = __expf(sB - mnew);
            const float p2 = __expf(sC - mnew);
            const float p3 = __expf(sD - mnew);
            float rs = (p0 + p1) + (p2 + p3);
            #pragma unroll
            for (int off = 1; off < 16; off <<= 1)
                rs += __shfl_xor(rs, off);
            l_i[r] = l_i[r] * corr + rs;
            m_i[r] = mnew;
            const int pr = prow_base + r * LDT;
            Ps[pr +  0] = f2h(p0);
            Ps[pr + 16] = f2h(p1);
            Ps[pr + 32] = f2h(p2);
            Ps[pr + 48] = f2h(p3);
            acc_o[0][r] *= corr; acc_o[1][r] *= corr;
            acc_o[2][r] *= corr; acc_o[3][r] *= corr;
        }

        // ---- PV: A = own-wave P rows (same-wave LDS in-order, no barrier),
        //          B = VT (swizzled) ----
        half8 pa0 = *(const half8*)&Ps[pa_row + l4 * 8];
        half8 pa1 = *(const half8*)&Ps[pa_row + 32 + l4 * 8];
        #pragma unroll
        for (int dt = 0; dt < 4; ++dt) {
            const int d = dt * 16 + l15;
            half8 vt0 = *(const half8*)&VTs[vt_idx(d, l4 * 8)];
            half8 vt1 = *(const half8*)&VTs[vt_idx(d, 32 + l4 * 8)];
            acc_o[dt] = MFMA16(pa0, vt0, acc_o[dt]);
            acc_o[dt] = MFMA16(pa1, vt1, acc_o[dt]);
        }

        __syncthreads();                 // everyone done reading Vs/VTs
        if (t + 1 < SEQ / 64) {
            stageV(t + 1);
            __syncthreads();             // new tile visible
        }
    }

    // ---- epilogue: normalize + store fp32 [B][S][H*D] ----
    #pragma unroll
    for (int r = 0; r < 4; ++r) {
        const float inv = 1.f / l_i[r];
        const int s = s0 + w * 16 + l4 * 4 + r;
        float* op = &out[((size_t)(b * SEQ + s)) * HID + h * HDIM + l15];
        op[ 0] = acc_o[0][r] * inv;
        op[16] = acc_o[1][r] * inv;
        op[32] = acc_o[2][r] * inv;
        op[48] = acc_o[3][r] * inv;
    }
}

// ---------------------------------------------------------------------------
extern "C" void kernel_launch(void* const* d_in, const int* in_sizes, int n_in,
                              void* d_out, int out_size, void* d_ws, size_t ws_size,
                              hipStream_t stream) {
    (void)in_sizes; (void)n_in; (void)out_size; (void)ws_size;
    const float* X  = (const float*)d_in[0];
    const float* Wq = (const float*)d_in[1];
    const float* bq = (const float*)d_in[2];
    // d_in[3] = Wk, d_in[4] = bk: unused by the reference output (source bug)
    const float* Wv = (const float*)d_in[5];
    const float* bv = (const float*)d_in[6];
    float* outp = (float*)d_out;

    char* ws = (char*)d_ws;
    _Float16* Xb  = (_Float16*)(ws);                        //  8 MB: [4096][1024]
    _Float16* WTq = (_Float16*)(ws + 8388608);              //  2 MB: [N][K]
    _Float16* WTv = (_Float16*)(ws + 8388608 + 2097152);    //  2 MB
    _Float16* Qb  = (_Float16*)(ws + 12582912);             //  8 MB: [B][H][S][D]
    _Float16* Vb  = (_Float16*)(ws + 20971520);             //  8 MB

    conv_x_kernel<<<2048, 256, 0, stream>>>(X, Xb, (BATCH * SEQ * EMB) / 4);
    conv_wt_kernel<<<dim3(16, 16), 256, 0, stream>>>(Wq, WTq);
    conv_wt_kernel<<<dim3(16, 16), 256, 0, stream>>>(Wv, WTv);
    proj_kernel<<<dim3(NHEAD, (BATCH * SEQ) / 128), 256, 0, stream>>>(
        Xb, WTq, WTv, bq, bv, Qb, Vb);
    attn_kernel<<<dim3(SEQ / 64, BATCH * NHEAD), 256, 0, stream>>>(Qb, Vb, outp);
}

// Round 4
// 218.517 us; speedup vs baseline: 1.1324x; 1.1324x over previous
//
#include <hip/hip_runtime.h>
#include <math.h>

// MultiHeadSelfAttention: B=2, S=2048, E=1024, H=16, D=64
// Reference computes Q@V^T (source bug, K unused) -> softmax -> @V.
// Round 3: conflict-free LDS (LDT=80), pre-transposed V^T written by proj,
// Ps XOR-swizzle + Qs/Ps overlay (5 blocks/CU), setprio, XCD-contiguous grid.

constexpr int BATCH = 2;
constexpr int SEQ   = 2048;
constexpr int EMB   = 1024;
constexpr int NHEAD = 16;
constexpr int HDIM  = 64;
constexpr int HID   = 1024;

typedef __attribute__((ext_vector_type(8))) _Float16 half8;
typedef __attribute__((ext_vector_type(4))) float    f32x4;

#define MFMA16(a, b, c) __builtin_amdgcn_mfma_f32_16x16x32_f16((a), (b), (c), 0, 0, 0)

// LDS leading dim (halves): 80 -> 40 dwords/row == 8 mod 32 -> frag reads
// (rows l15, 16B at 4*l4 dwords) hit banks 8*l15+4*l4: 2-way = free.
constexpr int LDT = 80;

__device__ __forceinline__ _Float16 f2h(float f) { return (_Float16)f; }

// ---------------------------------------------------------------------------
// conv_x: fp32 -> fp16 elementwise (X)
// ---------------------------------------------------------------------------
__global__ __launch_bounds__(256) void conv_x_kernel(
    const float* __restrict__ X, _Float16* __restrict__ Xb, int n4)
{
    union Pack { uint2 q; _Float16 e[4]; };
    int idx = blockIdx.x * 256 + threadIdx.x;
    int stride = gridDim.x * 256;
    for (int i = idx; i < n4; i += stride) {
        float4 v = ((const float4*)X)[i];
        Pack p;
        p.e[0] = f2h(v.x); p.e[1] = f2h(v.y);
        p.e[2] = f2h(v.z); p.e[3] = f2h(v.w);
        ((uint2*)Xb)[i] = p.q;
    }
}

// ---------------------------------------------------------------------------
// conv_wt: W [K=1024][N=1024] fp32  ->  WT [N][K] fp16 (transpose via LDS)
// ---------------------------------------------------------------------------
__global__ __launch_bounds__(256) void conv_wt_kernel(
    const float* __restrict__ W, _Float16* __restrict__ WT)
{
    __shared__ _Float16 T[64 * 68];
    const int tid = threadIdx.x;
    const int n0 = blockIdx.x * 64;
    const int k0 = blockIdx.y * 64;

    #pragma unroll
    for (int i = 0; i < 4; ++i) {
        const int u = tid + i * 256;
        const int r = u >> 4;              // k row
        const int c4 = (u & 15) << 2;      // n col
        const float4 v = *(const float4*)&W[(size_t)(k0 + r) * HID + n0 + c4];
        T[r * 68 + c4 + 0] = f2h(v.x);
        T[r * 68 + c4 + 1] = f2h(v.y);
        T[r * 68 + c4 + 2] = f2h(v.z);
        T[r * 68 + c4 + 3] = f2h(v.w);
    }
    __syncthreads();

    union Pack { uint4 q; _Float16 e[8]; };
    #pragma unroll
    for (int i = 0; i < 2; ++i) {
        const int u = tid + i * 256;
        const int n = u >> 3;
        const int kc = (u & 7) << 3;
        Pack p;
        #pragma unroll
        for (int j = 0; j < 8; ++j) p.e[j] = T[(kc + j) * 68 + n];
        *(uint4*)&WT[(size_t)(n0 + n) * EMB + k0 + kc] = p.q;
    }
}

// ---------------------------------------------------------------------------
// proj: Q = Xb@WTq^T + bq, V = Xb@WTv^T + bv
// Outputs: Qo, Vo fp16 [B][H][S][D]; VTo fp16 [B][H][D][S] (for attn PV).
// 128x64 tile, 4 waves, BK=64, mfma 16x16x32 f16. XCD-contiguous 1D grid.
// ---------------------------------------------------------------------------
__global__ __launch_bounds__(256) void proj_kernel(
    const _Float16* __restrict__ Xb, const _Float16* __restrict__ WTq,
    const _Float16* __restrict__ WTv, const float* __restrict__ bq,
    const float* __restrict__ bv, _Float16* __restrict__ Qo,
    _Float16* __restrict__ Vo, _Float16* __restrict__ VTo)
{
    __shared__ __align__(16) _Float16 Xs[128 * LDT];
    __shared__ __align__(16) _Float16 Wqs[64 * LDT];
    __shared__ __align__(16) _Float16 Wvs[64 * LDT];

    const int tid  = threadIdx.x;
    const int lane = tid & 63;
    const int w    = tid >> 6;
    // XCD-contiguous remap: 512 blocks, 64 per XCD, h-major so W tiles stay
    // resident in one XCD's L2.
    const int wg   = blockIdx.x;
    const int nid  = (wg & 7) * 64 + (wg >> 3);
    const int h    = nid >> 5;
    const int m0   = (nid & 31) * 128;
    const int n0   = h * HDIM;
    const int l15  = lane & 15;
    const int l4   = lane >> 4;

    f32x4 aq[2][4], av[2][4];
    #pragma unroll
    for (int mt = 0; mt < 2; ++mt)
        #pragma unroll
        for (int nt = 0; nt < 4; ++nt) {
            aq[mt][nt] = f32x4{0.f, 0.f, 0.f, 0.f};
            av[mt][nt] = f32x4{0.f, 0.f, 0.f, 0.f};
        }

    for (int k0 = 0; k0 < EMB; k0 += 64) {
        #pragma unroll
        for (int i = 0; i < 4; ++i) {
            const int u = tid + i * 256;
            const int r = u >> 3;
            const int c8 = (u & 7) << 3;
            *(uint4*)&Xs[r * LDT + c8] =
                *(const uint4*)&Xb[(size_t)(m0 + r) * EMB + k0 + c8];
        }
        #pragma unroll
        for (int i = 0; i < 2; ++i) {
            const int u = tid + i * 256;
            const int r = u >> 3;
            const int c8 = (u & 7) << 3;
            *(uint4*)&Wqs[r * LDT + c8] =
                *(const uint4*)&WTq[(size_t)(n0 + r) * EMB + k0 + c8];
            *(uint4*)&Wvs[r * LDT + c8] =
                *(const uint4*)&WTv[(size_t)(n0 + r) * EMB + k0 + c8];
        }
        __syncthreads();

        __builtin_amdgcn_s_setprio(1);
        #pragma unroll
        for (int kd = 0; kd < 2; ++kd) {
            const int ko = kd * 32 + l4 * 8;
            half8 xa0 = *(const half8*)&Xs[(w * 32 + l15) * LDT + ko];
            half8 xa1 = *(const half8*)&Xs[(w * 32 + 16 + l15) * LDT + ko];
            #pragma unroll
            for (int nt = 0; nt < 4; ++nt) {
                half8 wq = *(const half8*)&Wqs[(nt * 16 + l15) * LDT + ko];
                half8 wv = *(const half8*)&Wvs[(nt * 16 + l15) * LDT + ko];
                aq[0][nt] = MFMA16(xa0, wq, aq[0][nt]);
                aq[1][nt] = MFMA16(xa1, wq, aq[1][nt]);
                av[0][nt] = MFMA16(xa0, wv, av[0][nt]);
                av[1][nt] = MFMA16(xa1, wv, av[1][nt]);
            }
        }
        __builtin_amdgcn_s_setprio(0);
        __syncthreads();
    }

    // epilogue: bias + convert; Q,V row-major [B][H][S][D]; V^T [B][H][D][S]
    #pragma unroll
    for (int nt = 0; nt < 4; ++nt) {
        const int d = nt * 16 + l15;
        const float bqv = bq[n0 + d];
        const float bvv = bv[n0 + d];
        #pragma unroll
        for (int mt = 0; mt < 2; ++mt)
            #pragma unroll
            for (int r = 0; r < 4; ++r) {
                const int m = m0 + w * 32 + mt * 16 + l4 * 4 + r;
                const int bb = m >> 11;
                const int s  = m & (SEQ - 1);
                const int bh = bb * NHEAD + h;
                const float vval = av[mt][nt][r] + bvv;
                Qo[((size_t)bh * SEQ + s) * HDIM + d] = f2h(aq[mt][nt][r] + bqv);
                Vo[((size_t)bh * SEQ + s) * HDIM + d] = f2h(vval);
                VTo[((size_t)bh * HDIM + d) * SEQ + s] = f2h(vval);
            }
    }
}

// ---------------------------------------------------------------------------
// attn: per (b,h) flash attention. scores = Q@V^T/8 (source bug), softmax,
// @V. 64 Q-rows/block, 4 waves x 16 rows, KV tiles of 64.
// Vs (row-major V) feeds QK^T; VTs (from pre-transposed VTo) feeds PV.
// Ps overlays Qs (same wave-row regions); Ps chunks XOR-swizzled by row&7.
// ---------------------------------------------------------------------------
__global__ __launch_bounds__(256) void attn_kernel(
    const _Float16* __restrict__ Qw, const _Float16* __restrict__ Vw,
    const _Float16* __restrict__ VTw, float* __restrict__ out)
{
    __shared__ __align__(16) _Float16 PQs[64 * LDT];  // Qs then Ps (overlay)
    __shared__ __align__(16) _Float16 Vs[64 * LDT];
    __shared__ __align__(16) _Float16 VTs[64 * LDT];

    const int tid  = threadIdx.x;
    const int lane = tid & 63;
    const int w    = tid >> 6;
    const int l15  = lane & 15;
    const int l4   = lane >> 4;
    // XCD-contiguous remap: 1024 blocks, 128/XCD = 4 full bh groups -> V tile
    // stream stays in one XCD's L2.
    const int wg = blockIdx.x;
    const int nw = (wg & 7) * 128 + (wg >> 3);
    const int bh = nw >> 5;
    const int qb = nw & 31;
    const int b  = bh >> 4;
    const int h  = bh & (NHEAD - 1);
    const int s0 = qb * 64;

    const _Float16* Qp  = Qw  + (size_t)bh * SEQ * HDIM;
    const _Float16* Vp  = Vw  + (size_t)bh * SEQ * HDIM;
    const _Float16* VTp = VTw + (size_t)bh * HDIM * SEQ;

    // stage V tile t: Vs rows=k (from Vo), VTs rows=d (from VTo), all uint4
    auto stageV = [&](int t) {
        #pragma unroll
        for (int i = 0; i < 2; ++i) {
            const int u = tid + i * 256;
            const int r = u >> 3;
            const int c8 = (u & 7) << 3;
            *(uint4*)&Vs[r * LDT + c8] =
                *(const uint4*)&Vp[(size_t)(t * 64 + r) * HDIM + c8];
            *(uint4*)&VTs[r * LDT + c8] =
                *(const uint4*)&VTp[(size_t)r * SEQ + t * 64 + c8];
        }
    };

    // load Q tile into PQs
    #pragma unroll
    for (int i = 0; i < 2; ++i) {
        const int u = tid + i * 256;
        const int r = u >> 3;
        const int c8 = (u & 7) << 3;
        *(uint4*)&PQs[r * LDT + c8] =
            *(const uint4*)&Qp[(size_t)(s0 + r) * HDIM + c8];
    }
    stageV(0);
    __syncthreads();

    // hoist Q A-frags (each wave reads only its own 16 rows; those same rows
    // are the only PQs rows this wave later overwrites with P -> no barrier)
    const half8 qa0 = *(const half8*)&PQs[(w * 16 + l15) * LDT + l4 * 8];
    const half8 qa1 = *(const half8*)&PQs[(w * 16 + l15) * LDT + 32 + l4 * 8];

    f32x4 acc_o[4];
    #pragma unroll
    for (int dt = 0; dt < 4; ++dt) acc_o[dt] = f32x4{0.f, 0.f, 0.f, 0.f};
    float m_i[4] = {-INFINITY, -INFINITY, -INFINITY, -INFINITY};
    float l_i[4] = {0.f, 0.f, 0.f, 0.f};

    const int chi  = l15 >> 3;          // P-write chunk base parity
    const int hl   = l15 & 7;           // half within chunk
    const int rkey = l15 & 7;           // P-read swizzle key (row = w*16+l15)

    for (int t = 0; t < SEQ / 64; ++t) {
        // ---- QK^T: D[q][k], A = Q rows, B = V rows (Q@V^T directly) ----
        f32x4 acc_s[4];
        #pragma unroll
        for (int nt = 0; nt < 4; ++nt) acc_s[nt] = f32x4{0.f, 0.f, 0.f, 0.f};
        __builtin_amdgcn_s_setprio(1);
        #pragma unroll
        for (int nt = 0; nt < 4; ++nt) {
            half8 vb0 = *(const half8*)&Vs[(nt * 16 + l15) * LDT + l4 * 8];
            half8 vb1 = *(const half8*)&Vs[(nt * 16 + l15) * LDT + 32 + l4 * 8];
            acc_s[nt] = MFMA16(qa0, vb0, acc_s[nt]);
            acc_s[nt] = MFMA16(qa1, vb1, acc_s[nt]);
        }
        __builtin_amdgcn_s_setprio(0);

        // ---- online softmax (fp32); row q = w*16 + l4*4 + r, col = l15+16nt
        #pragma unroll
        for (int r = 0; r < 4; ++r) {
            float sA = acc_s[0][r] * 0.125f;
            float sB = acc_s[1][r] * 0.125f;
            float sC = acc_s[2][r] * 0.125f;
            float sD = acc_s[3][r] * 0.125f;
            float mloc = fmaxf(fmaxf(sA, sB), fmaxf(sC, sD));
            #pragma unroll
            for (int off = 1; off < 16; off <<= 1)
                mloc = fmaxf(mloc, __shfl_xor(mloc, off));
            const float mnew = fmaxf(m_i[r], mloc);
            const float corr = __expf(m_i[r] - mnew);
            const float p0 = __expf(sA - mnew);
            const float p1 = __expf(sB - mnew);
            const float p2 = __expf(sC - mnew);
            const float p3 = __expf(sD - mnew);
            float rs = (p0 + p1) + (p2 + p3);
            #pragma unroll
            for (int off = 1; off < 16; off <<= 1)
                rs += __shfl_xor(rs, off);
            l_i[r] = l_i[r] * corr + rs;
            m_i[r] = mnew;
            // P store, chunk-XOR-swizzled: elem(row,col) at chunk (col>>3)^(row&7)
            const int key = (l4 * 4 + r) & 7;
            _Float16* pr = &PQs[(w * 16 + l4 * 4 + r) * LDT];
            pr[(((0 + chi) ^ key) << 3) + hl] = f2h(p0);
            pr[(((2 + chi) ^ key) << 3) + hl] = f2h(p1);
            pr[(((4 + chi) ^ key) << 3) + hl] = f2h(p2);
            pr[(((6 + chi) ^ key) << 3) + hl] = f2h(p3);
            acc_o[0][r] *= corr; acc_o[1][r] *= corr;
            acc_o[2][r] *= corr; acc_o[3][r] *= corr;
        }

        // ---- PV: A = own-wave P rows (swizzled read), B = VT rows ----
        const _Float16* prd = &PQs[(w * 16 + l15) * LDT];
        half8 pa0 = *(const half8*)&prd[((l4 ^ rkey) << 3)];
        half8 pa1 = *(const half8*)&prd[(((4 + l4) ^ rkey) << 3)];
        __builtin_amdgcn_s_setprio(1);
        #pragma unroll
        for (int dt = 0; dt < 4; ++dt) {
            half8 vt0 = *(const half8*)&VTs[(dt * 16 + l15) * LDT + l4 * 8];
            half8 vt1 = *(const half8*)&VTs[(dt * 16 + l15) * LDT + 32 + l4 * 8];
            acc_o[dt] = MFMA16(pa0, vt0, acc_o[dt]);
            acc_o[dt] = MFMA16(pa1, vt1, acc_o[dt]);
        }
        __builtin_amdgcn_s_setprio(0);

        __syncthreads();
        if (t + 1 < SEQ / 64) {
            stageV(t + 1);
            __syncthreads();
        }
    }

    // ---- epilogue: normalize + store fp32 [B][S][H*D] ----
    #pragma unroll
    for (int r = 0; r < 4; ++r) {
        const float inv = 1.f / l_i[r];
        const int s = s0 + w * 16 + l4 * 4 + r;
        float* op = &out[((size_t)(b * SEQ + s)) * HID + h * HDIM + l15];
        op[ 0] = acc_o[0][r] * inv;
        op[16] = acc_o[1][r] * inv;
        op[32] = acc_o[2][r] * inv;
        op[48] = acc_o[3][r] * inv;
    }
}

// ---------------------------------------------------------------------------
extern "C" void kernel_launch(void* const* d_in, const int* in_sizes, int n_in,
                              void* d_out, int out_size, void* d_ws, size_t ws_size,
                              hipStream_t stream) {
    (void)in_sizes; (void)n_in; (void)out_size; (void)ws_size;
    const float* X  = (const float*)d_in[0];
    const float* Wq = (const float*)d_in[1];
    const float* bq = (const float*)d_in[2];
    // d_in[3] = Wk, d_in[4] = bk: unused by the reference output (source bug)
    const float* Wv = (const float*)d_in[5];
    const float* bv = (const float*)d_in[6];
    float* outp = (float*)d_out;

    char* ws = (char*)d_ws;
    _Float16* Xb  = (_Float16*)(ws);                    //  8 MB [4096][1024]
    _Float16* WTq = (_Float16*)(ws + (8u  << 20));      //  2 MB [N][K]
    _Float16* WTv = (_Float16*)(ws + (10u << 20));      //  2 MB
    _Float16* Qb  = (_Float16*)(ws + (12u << 20));      //  8 MB [B][H][S][D]
    _Float16* Vb  = (_Float16*)(ws + (20u << 20));      //  8 MB [B][H][S][D]
    _Float16* VTb = (_Float16*)(ws + (28u << 20));      //  8 MB [B][H][D][S]

    conv_x_kernel<<<2048, 256, 0, stream>>>(X, Xb, (BATCH * SEQ * EMB) / 4);
    conv_wt_kernel<<<dim3(16, 16), 256, 0, stream>>>(Wq, WTq);
    conv_wt_kernel<<<dim3(16, 16), 256, 0, stream>>>(Wv, WTv);
    proj_kernel<<<512, 256, 0, stream>>>(Xb, WTq, WTv, bq, bv, Qb, Vb, VTb);
    attn_kernel<<<1024, 256, 0, stream>>>(Qb, Vb, VTb, outp);
}